// Round 6
// baseline (194.121 us; speedup 1.0000x reference)
//
#include <hip/hip_runtime.h>
#include <math.h>

#define N_LAYERS 8
#define TAB 40
#define TABSZ (TAB * TAB)
#define LOG2E2 2.8853900817779268f   // 2*log2(e)
#define NLOG2E 1.4426950408889634f   // log2(e)
#define UCLAMP 24.0f                  // exp2 clamp: 4-product <= 2^96

#if __has_builtin(__builtin_amdgcn_exp2f)
__device__ __forceinline__ float exp2_fast(float x) { return __builtin_amdgcn_exp2f(x); }
#else
__device__ __forceinline__ float exp2_fast(float x) { return __expf(0.6931471805599453f * x); }
#endif

// d_ws float layout:
//  [0..5]   log2-domain input layer (W~ 4, b~ 2)
//  [6..9]   C0,C1,D0,D1   (u = C - D*i table-coord map)
//  [10..13] lo0,lo1,h0,h1 (table domain)
//  [16 ..]              gt   : unpacked g table, TABSZ floats
//  [16+TABSZ ..]        gt4  : packed CR rows, TABSZ float4 (16B aligned)
__global__ void setup_meta(const float* __restrict__ W0, const float* __restrict__ b0,
                           const float* __restrict__ s0, const float* __restrict__ t0,
                           float* __restrict__ fp) {
    if (threadIdx.x == 0 && blockIdx.x == 0) {
        fp[0] = LOG2E2 * W0[0]; fp[1] = LOG2E2 * W0[1];
        fp[2] = LOG2E2 * W0[2]; fp[3] = LOG2E2 * W0[3];
        fp[4] = LOG2E2 * b0[0]; fp[5] = LOG2E2 * b0[1];
        for (int c = 0; c < 2; ++c) {
            float s = s0[c], t = t0[c];
            float span = fmaxf(2.2f * s, 1e-5f);   // 10% pad each side; u lands in [1.7,37.3]
            float h  = span / (float)(TAB - 1);
            float lo = t - 0.5f * span;
            float ih = (float)(TAB - 1) / span;
            fp[6 + c]  = (s + 0.5f * span) * ih;   // C
            fp[8 + c]  = 2.0f * s * ih;            // D
            fp[10 + c] = lo;
            fp[12 + c] = h;
        }
    }
}

// Exact evaluation of layers 1..8 + head on the grid (one-time, tanhf).
__global__ void build_table(const float* __restrict__ Ws, const float* __restrict__ bs,
                            const float* __restrict__ ss, const float* __restrict__ ts,
                            const float* __restrict__ Wf, const float* __restrict__ bf,
                            const float* __restrict__ fp, float* __restrict__ gt) {
    int idx = blockIdx.x * 256 + threadIdx.x;
    if (idx >= TABSZ) return;
    int k1 = idx / TAB, k0 = idx - k1 * TAB;
    float z0 = fp[10] + (float)k0 * fp[12];
    float z1 = fp[11] + (float)k1 * fp[13];
    for (int l = 0; l < N_LAYERS; ++l) {
        float u0 = fmaf(z0, Ws[4 * l + 0], fmaf(z1, Ws[4 * l + 1], bs[2 * l + 0]));
        float u1 = fmaf(z0, Ws[4 * l + 2], fmaf(z1, Ws[4 * l + 3], bs[2 * l + 1]));
        z0 = fmaf(tanhf(u0), ss[2 * l + 0], ts[2 * l + 0]);
        z1 = fmaf(tanhf(u1), ss[2 * l + 1], ts[2 * l + 1]);
    }
    gt[idx] = fmaf(z0, Wf[0], fmaf(z1, Wf[1], bf[0]));
}

// Pack Catmull-Rom row taps: gt4[iy*TAB+ix] = g[iy][ix-1..ix+2] (cols clamped).
__global__ void pack_table(const float* __restrict__ gt, float4* __restrict__ gt4) {
    int idx = blockIdx.x * 256 + threadIdx.x;
    if (idx >= TABSZ) return;
    int iy = idx / TAB, ix = idx - iy * TAB;
    const float* row = gt + iy * TAB;
    int c0 = max(ix - 1, 0);
    int c1 = ix;
    int c2 = min(ix + 1, TAB - 1);
    int c3 = min(ix + 2, TAB - 1);
    gt4[idx] = make_float4(row[c0], row[c1], row[c2], row[c3]);
}

// Catmull-Rom weights.
__device__ __forceinline__ void cr_w(float f, float w[4]) {
    w[0] = f * fmaf(f, fmaf(f, -0.5f, 1.0f), -0.5f);
    w[1] = fmaf(f * f, fmaf(f, 1.5f, -2.5f), 1.0f);
    w[2] = f * fmaf(f, fmaf(f, -1.5f, 2.0f), 0.5f);
    w[3] = f * f * fmaf(f, 0.5f, -0.5f);
}

// Both nets' table lookups fused: 8 ds_read_b128 outstanding together.
__device__ __forceinline__ float interp_two(const float4* __restrict__ tab4,
                                            float ax0, float ax1, float ay0, float ay1) {
    int ixa = min(max((int)ax0, 1), TAB - 3);
    int iya = min(max((int)ax1, 1), TAB - 3);
    int ixb = min(max((int)ay0, 1), TAB - 3);
    int iyb = min(max((int)ay1, 1), TAB - 3);
    float fxa = ax0 - (float)ixa, fya = ax1 - (float)iya;
    float fxb = ay0 - (float)ixb, fyb = ay1 - (float)iyb;

    const float4* pa = tab4 + (iya - 1) * TAB + ixa;
    const float4* pb = tab4 + (iyb - 1) * TAB + ixb;
    float4 a0 = pa[0], a1 = pa[TAB], a2 = pa[2 * TAB], a3 = pa[3 * TAB];
    float4 b0 = pb[0], b1 = pb[TAB], b2 = pb[2 * TAB], b3 = pb[3 * TAB];

    float wxa[4], wya[4], wxb[4], wyb[4];
    cr_w(fxa, wxa); cr_w(fya, wya);
    cr_w(fxb, wxb); cr_w(fyb, wyb);

    float ra0 = fmaf(a0.w, wxa[3], fmaf(a0.z, wxa[2], fmaf(a0.y, wxa[1], a0.x * wxa[0])));
    float ra1 = fmaf(a1.w, wxa[3], fmaf(a1.z, wxa[2], fmaf(a1.y, wxa[1], a1.x * wxa[0])));
    float ra2 = fmaf(a2.w, wxa[3], fmaf(a2.z, wxa[2], fmaf(a2.y, wxa[1], a2.x * wxa[0])));
    float ra3 = fmaf(a3.w, wxa[3], fmaf(a3.z, wxa[2], fmaf(a3.y, wxa[1], a3.x * wxa[0])));
    float gx  = fmaf(ra3, wya[3], fmaf(ra2, wya[2], fmaf(ra1, wya[1], ra0 * wya[0])));

    float rb0 = fmaf(b0.w, wxb[3], fmaf(b0.z, wxb[2], fmaf(b0.y, wxb[1], b0.x * wxb[0])));
    float rb1 = fmaf(b1.w, wxb[3], fmaf(b1.z, wxb[2], fmaf(b1.y, wxb[1], b1.x * wxb[0])));
    float rb2 = fmaf(b2.w, wxb[3], fmaf(b2.z, wxb[2], fmaf(b2.y, wxb[1], b2.x * wxb[0])));
    float rb3 = fmaf(b3.w, wxb[3], fmaf(b3.z, wxb[2], fmaf(b3.y, wxb[1], b3.x * wxb[0])));
    float gy  = fmaf(rb3, wyb[3], fmaf(rb2, wyb[2], fmaf(rb1, wyb[1], rb0 * wyb[0])));

    return gx * gy;
}

// One pair: exact log2-domain input layer + Montgomery-4 rcp, then fused lookups.
__device__ __forceinline__ float pair_val(const float4* __restrict__ tab4,
                                          float px0, float px1, float py0, float py1,
                                          float C0, float C1, float D0, float D1) {
    float d0 = exp2_fast(fminf(px0, UCLAMP)) + 1.0f;
    float d1 = exp2_fast(fminf(px1, UCLAMP)) + 1.0f;
    float d2 = exp2_fast(fminf(py0, UCLAMP)) + 1.0f;
    float d3 = exp2_fast(fminf(py1, UCLAMP)) + 1.0f;
    float p2 = d0 * d1, p3 = p2 * d2, p4 = p3 * d3;
    float R = __builtin_amdgcn_rcpf(p4);
    float i3 = R * p3;  R *= d3;
    float i2 = R * p2;  R *= d2;
    float i1 = R * d0;
    float i0 = R * d1;
    float ux0 = fmaf(-D0, i0, C0), ux1 = fmaf(-D1, i1, C1);
    float uy0 = fmaf(-D0, i2, C0), uy1 = fmaf(-D1, i3, C1);
    return interp_two(tab4, ux0, ux1, uy0, uy1);
}

__global__ __launch_bounds__(256) void fraud_kernel(
    const float4* __restrict__ x4, const float4* __restrict__ y4,
    const float* __restrict__ fp, const float4* __restrict__ gt4,
    float2* __restrict__ out2, int stride)   // 4 float4-groups (8 pairs) per thread
{
    __shared__ float4 tab4[TABSZ];   // 25.6 KB packed CR rows -> 6 blocks/CU
    for (int j = threadIdx.x; j < TABSZ; j += 256) tab4[j] = gt4[j];
    __syncthreads();

    float Wt0 = fp[0], Wt1 = fp[1], Wt2 = fp[2], Wt3 = fp[3];
    float bt0 = fp[4], bt1 = fp[5];
    float C0 = fp[6], C1 = fp[7], D0 = fp[8], D1 = fp[9];

    int tid = blockIdx.x * 256 + threadIdx.x;

    // ---- load phase: all 8 float4 up front (one VMEM latency) ----
    float4 xs[4], ys[4];
#pragma unroll
    for (int k = 0; k < 4; ++k) {
        xs[k] = x4[tid + k * stride];
        ys[k] = y4[tid + k * stride];
    }

    // ---- compute phase ----
#pragma unroll
    for (int k = 0; k < 4; ++k) {
        float4 xa = xs[k], ya = ys[k];   // 2 pairs

        float pxa0 = fmaf(xa.x, Wt0, fmaf(xa.y, Wt1, bt0));
        float pxa1 = fmaf(xa.x, Wt2, fmaf(xa.y, Wt3, bt1));
        float pya0 = fmaf(ya.x, Wt0, fmaf(ya.y, Wt1, bt0));
        float pya1 = fmaf(ya.x, Wt2, fmaf(ya.y, Wt3, bt1));
        float dxA = xa.x - ya.x, dyA = xa.y - ya.y;
        float rA = exp2_fast(-NLOG2E * fmaf(dxA, dxA, dyA * dyA));
        float resA = rA * pair_val(tab4, pxa0, pxa1, pya0, pya1, C0, C1, D0, D1);

        float pxb0 = fmaf(xa.z, Wt0, fmaf(xa.w, Wt1, bt0));
        float pxb1 = fmaf(xa.z, Wt2, fmaf(xa.w, Wt3, bt1));
        float pyb0 = fmaf(ya.z, Wt0, fmaf(ya.w, Wt1, bt0));
        float pyb1 = fmaf(ya.z, Wt2, fmaf(ya.w, Wt3, bt1));
        float dxB = xa.z - ya.z, dyB = xa.w - ya.w;
        float rB = exp2_fast(-NLOG2E * fmaf(dxB, dxB, dyB * dyB));
        float resB = rB * pair_val(tab4, pxb0, pxb1, pyb0, pyb1, C0, C1, D0, D1);

        out2[tid + k * stride] = make_float2(resA, resB);
    }
}

extern "C" void kernel_launch(void* const* d_in, const int* in_sizes, int n_in,
                              void* d_out, int out_size, void* d_ws, size_t ws_size,
                              hipStream_t stream) {
    const float* x  = (const float*)d_in[0];
    const float* y  = (const float*)d_in[1];
    const float* W0 = (const float*)d_in[2];
    const float* b0 = (const float*)d_in[3];
    const float* s0 = (const float*)d_in[4];
    const float* t0 = (const float*)d_in[5];
    const float* Ws = (const float*)d_in[6];
    const float* bs = (const float*)d_in[7];
    const float* ss = (const float*)d_in[8];
    const float* ts = (const float*)d_in[9];
    const float* Wf = (const float*)d_in[10];
    const float* bf = (const float*)d_in[11];
    float* out = (float*)d_out;
    float* fp  = (float*)d_ws;
    float* gt  = fp + 16;
    float4* gt4 = (float4*)(fp + 16 + TABSZ);   // 16B-aligned (16+1600 floats)

    hipLaunchKernelGGL(setup_meta, dim3(1), dim3(64), 0, stream, W0, b0, s0, t0, fp);
    hipLaunchKernelGGL(build_table, dim3((TABSZ + 255) / 256), dim3(256), 0, stream,
                       Ws, bs, ss, ts, Wf, bf, fp, gt);
    hipLaunchKernelGGL(pack_table, dim3((TABSZ + 255) / 256), dim3(256), 0, stream,
                       gt, gt4);

    int n       = out_size;          // 8,388,608 pairs
    int ngroups = n / 2;             // float4-groups of 2 pairs
    int threads = ngroups / 4;       // 4 groups per thread = 8 pairs
    dim3 block(256);
    dim3 grid(threads / 256);
    hipLaunchKernelGGL(fraud_kernel, grid, block, 0, stream,
                       (const float4*)x, (const float4*)y, fp, gt4,
                       (float2*)out, threads);
}